// Round 24
// baseline (30.961 us; speedup 1.0000x reference)
//
#include <hip/hip_runtime.h>
#include <hip/hip_bf16.h>
#include <stdint.h>

#define IN_F 2048
#define OUT_F 128
#define KD 32
#define NR 256
#define OC 2176          // IN_F + OUT_F
#define OD 4096          // OUT_F * KD (T row stride)
#define THRESH 32.0f
#define KSN 32           // k-slices of 64
#define OPN (1024 * 256) // elems per Pp partial (8 projections per f)

typedef __bf16 bf16x8 __attribute__((ext_vector_type(8)));
typedef __bf16 bf16x4 __attribute__((ext_vector_type(4)));
typedef float  f32x4  __attribute__((ext_vector_type(4)));
typedef uint16_t u16x8 __attribute__((ext_vector_type(8)));

// ---------------------------------------------------------------------------
// K1 (R24): fused tproj + sgemm + x-copy at 4 blocks/CU.
// Grid 1024 = (32 ks of 64 k) x (32 fo of 4 f); LDS ~37 KB -> 4 blocks/CU,
// 16 waves/CU (R18 showed 2-block/CU version latency-bound at 19% occ).
// tproj is SINGLE-round: thread t owns (kl = t>>2, fl = t&3); its 8 T-loads
// and 8 x-loads all issue up front. Butterfly-FWHT (8 Walsh projections,
// masks {0,1,2,4,8,16,3,24}) -> Bs[o'][k] with conflict-free rotated write
// (bank = 4p, fl-independent). Then 2 MFMA chunks of 32 k, A-frags staged
// via the R17-proven coalesced As dbuf. Epilogue bf16 Pp[ks][o'][n].
// ---------------------------------------------------------------------------
__global__ __launch_bounds__(256, 4) void fused_kernel(const float* __restrict__ x,
                                                       const float* __restrict__ Tm,
                                                       float* __restrict__ out,
                                                       __bf16* __restrict__ Pp) {
    __shared__ __bf16 Bs[32][72];        // Tproj [o'_local][k_local], pad 8 (4.6 KB)
    __shared__ __bf16 As[2][4][256][8];  // x A-frag dbuf (32 KB)

    const int tid  = threadIdx.x;
    const int lane = tid & 63;
    const int wid  = tid >> 6;
    const int fr   = lane & 15, fg = lane >> 4;
    const int bid  = blockIdx.x;
    const int ks   = bid & 31;           // 64-k slice
    const int fo   = bid >> 5;           // f-group of 4
    const int k0   = ks * 64;

    // ---- x -> out copy (blocks 0..511 cover all 256 rows, 4 KB each)
    if (bid < 512) {
        const int row = bid >> 1;
        const int off = (bid & 1) * 1024 + tid * 4;
        float4 v = *reinterpret_cast<const float4*>(&x[row * IN_F + off]);
        *reinterpret_cast<float4*>(&out[row * OC + off]) = v;
    }

    // ---- issue x chunk-0 loads early
    float4 xs[8];
    const int kslot = tid & 7;
    const int nrow8 = tid >> 3;          // n = p*32 + nrow8
    #pragma unroll
    for (int p = 0; p < 8; ++p)
        xs[p] = *reinterpret_cast<const float4*>(&x[(p * 32 + nrow8) * IN_F + k0 + kslot * 4]);

    // ---- tproj: single round, 1 (k,f) pair per thread
    {
        const int fl = tid & 3;
        const int kl = tid >> 2;         // 0..63
        const float* src = Tm + (size_t)(k0 + kl) * OD + (fo * 4 + fl) * KD;

        float v[32];
        #pragma unroll
        for (int q = 0; q < 8; ++q) {
            f32x4 w = *reinterpret_cast<const f32x4*>(src + q * 4);
            v[q * 4]     = w[0];
            v[q * 4 + 1] = w[1];
            v[q * 4 + 2] = w[2];
            v[q * 4 + 3] = w[3];
        }

        float s1[16], d1[16];
        #pragma unroll
        for (int e = 0; e < 16; ++e) { s1[e] = v[2*e] + v[2*e+1]; d1[e] = v[2*e] - v[2*e+1]; }
        float s2[8], d2[8];
        #pragma unroll
        for (int e = 0; e < 8; ++e)  { s2[e] = s1[2*e] + s1[2*e+1]; d2[e] = s1[2*e] - s1[2*e+1]; }
        float s3[4], d3[4];
        #pragma unroll
        for (int e = 0; e < 4; ++e)  { s3[e] = s2[2*e] + s2[2*e+1]; d3[e] = s2[2*e] - s2[2*e+1]; }
        float s4[2], d4[2];
        #pragma unroll
        for (int e = 0; e < 2; ++e)  { s4[e] = s3[2*e] + s3[2*e+1]; d4[e] = s3[2*e] - s3[2*e+1]; }
        const float s5 = s4[0] + s4[1];
        const float d5 = s4[0] - s4[1];

        float pr[8];
        pr[0] = s5;
        { float s = 0.f;
          #pragma unroll
          for (int e = 0; e < 16; ++e) s += d1[e];
          pr[1] = s; }
        { float s = 0.f;
          #pragma unroll
          for (int e = 0; e < 8; ++e) s += d2[e];
          pr[2] = s; }
        pr[3] = (d3[0] + d3[1]) + (d3[2] + d3[3]);
        pr[4] = d4[0] + d4[1];
        pr[5] = d5;
        { float s = 0.f;
          #pragma unroll
          for (int g = 0; g < 8; ++g) s += d1[2*g] - d1[2*g+1];
          pr[6] = s; }
        pr[7] = s3[0] - s3[1] - s3[2] + s3[3];

        // conflict-free rotated write: bank = 4*p (fl-independent)
        #pragma unroll
        for (int pp = 0; pp < 8; ++pp) {
            const int p = (pp + fl * 2) & 7;
            Bs[fl * 8 + p][kl] = (__bf16)pr[p];
        }
    }

    // ---- write x chunk 0 into As[0]
    #pragma unroll
    for (int p = 0; p < 8; ++p) {
        bf16x4 b = { (__bf16)xs[p].x, (__bf16)xs[p].y, (__bf16)xs[p].z, (__bf16)xs[p].w };
        *reinterpret_cast<bf16x4*>(&As[0][kslot >> 1][p * 32 + nrow8][(kslot & 1) * 4]) = b;
    }
    __syncthreads();

    // ---- MFMA loop: 2 chunks of 32 k; acc[mi][oi], wave owns 64 n x 32 o'
    f32x4 acc[4][2] = {};

    #pragma unroll 1
    for (int c = 0; c < 2; ++c) {
        const int buf = c & 1;
        if (c < 1) {
            #pragma unroll
            for (int p = 0; p < 8; ++p)
                xs[p] = *reinterpret_cast<const float4*>(
                    &x[(p * 32 + nrow8) * IN_F + k0 + 32 + kslot * 4]);
        }

        bf16x8 bfrag[2];
        #pragma unroll
        for (int oi = 0; oi < 2; ++oi)
            bfrag[oi] = *reinterpret_cast<const bf16x8*>(&Bs[oi * 16 + fr][c * 32 + fg * 8]);
        #pragma unroll
        for (int mi = 0; mi < 4; ++mi) {
            bf16x8 af = *reinterpret_cast<const bf16x8*>(&As[buf][fg][wid * 64 + mi * 16 + fr][0]);
            acc[mi][0] = __builtin_amdgcn_mfma_f32_16x16x32_bf16(af, bfrag[0], acc[mi][0], 0, 0, 0);
            acc[mi][1] = __builtin_amdgcn_mfma_f32_16x16x32_bf16(af, bfrag[1], acc[mi][1], 0, 0, 0);
        }

        if (c < 1) {
            __syncthreads();             // all waves done reading As[1]? (dbuf swap)
            #pragma unroll
            for (int p = 0; p < 8; ++p) {
                bf16x4 b = { (__bf16)xs[p].x, (__bf16)xs[p].y, (__bf16)xs[p].z, (__bf16)xs[p].w };
                *reinterpret_cast<bf16x4*>(&As[1][kslot >> 1][p * 32 + nrow8][(kslot & 1) * 4]) = b;
            }
            __syncthreads();
        }
    }

    // ---- epilogue: Pp[ks][o' = fo*32 + oi*16 + fr][n = wid*64+mi*16+fg*4+r] bf16
    __bf16* dst = Pp + (size_t)ks * OPN;
    #pragma unroll
    for (int mi = 0; mi < 4; ++mi) {
        #pragma unroll
        for (int oi = 0; oi < 2; ++oi) {
            const int op = fo * 32 + oi * 16 + fr;
            const int nb = wid * 64 + mi * 16 + fg * 4;
            bf16x4 v = { (__bf16)acc[mi][oi][0], (__bf16)acc[mi][oi][1],
                         (__bf16)acc[mi][oi][2], (__bf16)acc[mi][oi][3] };
            *reinterpret_cast<bf16x4*>(&dst[(size_t)op * NR + nb]) = v;
        }
    }
}

// ---------------------------------------------------------------------------
// K2 (verbatim R23 two-tier, KSN=32): tier-1 = projections 0-3 (one
// broadcast b128 + 4 |d| + max tree); tier-1 survivors check projections
// 4-7 from LDS; exact fallback only if ALL 8 pass (identical accept
// condition to R17, which measured zero fallback events). Output exact.
// ---------------------------------------------------------------------------
__global__ __launch_bounds__(256, 2) void screen_kernel(const __bf16* __restrict__ Pp,
                                                        const float* __restrict__ x,
                                                        const float* __restrict__ Tm,
                                                        float* __restrict__ out) {
    __shared__ float P8s[256][8];
    __shared__ float part[4][64];

    const int f    = blockIdx.x;
    const int jq   = blockIdx.y;
    const int tid  = threadIdx.x;
    const int lane = tid & 63;
    const int wid  = tid >> 6;
    const int j    = jq * 64 + lane;

    // stage merged projections (32 bf16 partials, vectorized u16x8)
    {
        const int p  = tid >> 5;
        const int n0 = (tid & 31) * 8;
        const uint16_t* base = reinterpret_cast<const uint16_t*>(Pp)
                             + (size_t)(f * 8 + p) * NR + n0;
        float a[8] = {};
        #pragma unroll
        for (int ks = 0; ks < KSN; ++ks) {
            u16x8 v = *reinterpret_cast<const u16x8*>(base + (size_t)ks * OPN);
            #pragma unroll
            for (int e = 0; e < 8; ++e)
                a[e] += __builtin_bit_cast(float, (uint32_t)v[e] << 16);
        }
        #pragma unroll
        for (int e = 0; e < 8; ++e)
            P8s[n0 + e][p] = a[e];
    }
    __syncthreads();

    const f32x4 qj0 = *reinterpret_cast<const f32x4*>(&P8s[j][0]);
    const f32x4 qj1 = *reinterpret_cast<const f32x4*>(&P8s[j][4]);

    float acc = 0.f;
    const int i0 = wid * 64;
    #pragma unroll 2
    for (int ii = 0; ii < 64; ++ii) {
        const int i = i0 + ii;
        // tier 1: projections 0-3 (one broadcast b128)
        f32x4 r0 = *reinterpret_cast<const f32x4*>(&P8s[i][0]);
        f32x4 d0 = r0 - qj0;
        const float mx1 = fmaxf(fmaxf(fabsf(d0[0]), fabsf(d0[1])),
                                fmaxf(fabsf(d0[2]), fabsf(d0[3])));
        const bool ok1 = (mx1 < THRESH) && (i != j);

        if (__builtin_expect(__any(ok1), 0)) {
            // tier 2: projections 4-7 (rare)
            bool ok2 = false;
            if (ok1) {
                f32x4 r1 = *reinterpret_cast<const f32x4*>(&P8s[i][4]);
                f32x4 d1 = r1 - qj1;
                const float mx2 = fmaxf(fmaxf(fabsf(d1[0]), fabsf(d1[1])),
                                        fmaxf(fabsf(d1[2]), fabsf(d1[3])));
                ok2 = mx2 < THRESH;
            }
            if (__builtin_expect(__any(ok2), 0)) {
                if (ok2) {
                    // exact fallback (all 8 projections passed; ~never)
                    f32x4 ad[8] = {};
                    const float* xi = x + (size_t)i * IN_F;
                    const float* xj = x + (size_t)j * IN_F;
                    for (int k = 0; k < IN_F; ++k) {
                        const float dk = xi[k] - xj[k];
                        const float* tr = Tm + (size_t)k * OD + f * KD;
                        #pragma unroll
                        for (int q = 0; q < 8; ++q) {
                            f32x4 tv = *reinterpret_cast<const f32x4*>(tr + q * 4);
                            ad[q] += dk * tv;
                        }
                    }
                    float norm = 0.f;
                    #pragma unroll
                    for (int q = 0; q < 8; ++q)
                        norm += fabsf(ad[q][0]) + fabsf(ad[q][1])
                              + fabsf(ad[q][2]) + fabsf(ad[q][3]);
                    acc += __expf(-norm);
                }
            }
        }
    }

    if (wid == jq) acc += 1.0f;          // diagonal exp(0)=1, exact

    part[wid][lane] = acc;
    __syncthreads();
    if (tid < 64) {
        float s = part[0][tid] + part[1][tid] + part[2][tid] + part[3][tid];
        out[(jq * 64 + tid) * OC + IN_F + f] = s;
    }
}

extern "C" void kernel_launch(void* const* d_in, const int* in_sizes, int n_in,
                              void* d_out, int out_size, void* d_ws, size_t ws_size,
                              hipStream_t stream) {
    const float* x  = (const float*)d_in[0];   // [256, 2048] f32
    const float* Tm = (const float*)d_in[1];   // [2048, 4096] f32
    float* out = (float*)d_out;                // [256, 2176] f32

    __bf16* Pp = (__bf16*)d_ws;                // 16 MB: 32 bf16 o'-major partials

    fused_kernel<<<dim3(1024), 256, 0, stream>>>(x, Tm, out, Pp);
    screen_kernel<<<dim3(128, 4), 256, 0, stream>>>(Pp, x, Tm, out);
}

// Round 25
// 27.672 us; speedup vs baseline: 1.1188x; 1.1188x over previous
//
#include <hip/hip_runtime.h>
#include <hip/hip_bf16.h>
#include <stdint.h>

#define IN_F 2048
#define OUT_F 128
#define KD 32
#define NR 256
#define OC 2176          // IN_F + OUT_F
#define OD 4096          // OUT_F * KD (T row stride)
#define THRESH 32.0f
#define KSN 16           // k-slices of 128
#define OPN (1024 * 256) // elems per Pp partial (8 projections per f)

typedef __bf16 bf16x8 __attribute__((ext_vector_type(8)));
typedef __bf16 bf16x4 __attribute__((ext_vector_type(4)));
typedef float  f32x4  __attribute__((ext_vector_type(4)));
typedef uint16_t u16x8 __attribute__((ext_vector_type(8)));

// ---------------------------------------------------------------------------
// K1 (R17/R23 verbatim, best-measured): fused tproj + sgemm + x-copy.
// Block = (ks in [0,16), fo in [0,32)). T slab read once -> butterfly ->
// Tproj LDS (8 Walsh projections, masks {0,1,2,4,8,16,3,24}); x staged
// inline as MFMA A-frags (dbuf); bf16 Pp[ks][o'=f*8+p][n] partials.
// ---------------------------------------------------------------------------
__global__ __launch_bounds__(256, 2) void fused_kernel(const float* __restrict__ x,
                                                       const float* __restrict__ Tm,
                                                       float* __restrict__ out,
                                                       __bf16* __restrict__ Pp) {
    __shared__ __bf16 Bs[32][136];       // Tproj slab [o'_local][k_local], pad 8
    __shared__ __bf16 As[2][4][256][8];  // x A-frag dbuf (32 KB)

    const int tid  = threadIdx.x;
    const int lane = tid & 63;
    const int wid  = tid >> 6;
    const int fr   = lane & 15, fg = lane >> 4;
    const int bid  = blockIdx.x;
    const int ks   = bid & 15;
    const int fo   = bid >> 4;           // f-group of 4
    const int k0   = ks * 128;

    // ---- x -> out copy (block covers 4 KB: row bid>>1, half bid&1)
    {
        const int row = bid >> 1;
        const int off = (bid & 1) * 1024 + tid * 4;
        float4 v = *reinterpret_cast<const float4*>(&x[row * IN_F + off]);
        *reinterpret_cast<float4*>(&out[row * OC + off]) = v;
    }

    // ---- issue x chunk-0 loads early (latency hides under butterflies)
    float4 xs[8];
    const int kslot = tid & 7;
    const int nrow8 = tid >> 3;          // n = p*32 + nrow8
    #pragma unroll
    for (int p = 0; p < 8; ++p)
        xs[p] = *reinterpret_cast<const float4*>(&x[(p * 32 + nrow8) * IN_F + k0 + kslot * 4]);

    // ---- tproj: 2 (k,f) pairs per thread (sequential; keeps VGPR < 128)
    #pragma unroll 1
    for (int r = 0; r < 2; ++r) {
        const int idx = r * 256 + tid;
        const int fl  = idx & 3;
        const int kl  = idx >> 2;        // 0..127
        const float* src = Tm + (size_t)(k0 + kl) * OD + (fo * 4 + fl) * KD;

        float v[32];
        #pragma unroll
        for (int q = 0; q < 8; ++q) {
            f32x4 w = *reinterpret_cast<const f32x4*>(src + q * 4);
            v[q * 4]     = w[0];
            v[q * 4 + 1] = w[1];
            v[q * 4 + 2] = w[2];
            v[q * 4 + 3] = w[3];
        }

        float s1[16], d1[16];
        #pragma unroll
        for (int e = 0; e < 16; ++e) { s1[e] = v[2*e] + v[2*e+1]; d1[e] = v[2*e] - v[2*e+1]; }
        float s2[8], d2[8];
        #pragma unroll
        for (int e = 0; e < 8; ++e)  { s2[e] = s1[2*e] + s1[2*e+1]; d2[e] = s1[2*e] - s1[2*e+1]; }
        float s3[4], d3[4];
        #pragma unroll
        for (int e = 0; e < 4; ++e)  { s3[e] = s2[2*e] + s2[2*e+1]; d3[e] = s2[2*e] - s2[2*e+1]; }
        float s4[2], d4[2];
        #pragma unroll
        for (int e = 0; e < 2; ++e)  { s4[e] = s3[2*e] + s3[2*e+1]; d4[e] = s3[2*e] - s3[2*e+1]; }
        const float s5 = s4[0] + s4[1];
        const float d5 = s4[0] - s4[1];

        float pr[8];
        pr[0] = s5;
        { float s = 0.f;
          #pragma unroll
          for (int e = 0; e < 16; ++e) s += d1[e];
          pr[1] = s; }
        { float s = 0.f;
          #pragma unroll
          for (int e = 0; e < 8; ++e) s += d2[e];
          pr[2] = s; }
        pr[3] = (d3[0] + d3[1]) + (d3[2] + d3[3]);
        pr[4] = d4[0] + d4[1];
        pr[5] = d5;
        { float s = 0.f;
          #pragma unroll
          for (int g = 0; g < 8; ++g) s += d1[2*g] - d1[2*g+1];
          pr[6] = s; }
        pr[7] = s3[0] - s3[1] - s3[2] + s3[3];

        #pragma unroll
        for (int p = 0; p < 8; ++p)
            Bs[fl * 8 + p][kl] = (__bf16)pr[p];
    }

    // ---- write x chunk 0 into As[0]
    #pragma unroll
    for (int p = 0; p < 8; ++p) {
        bf16x4 b = { (__bf16)xs[p].x, (__bf16)xs[p].y, (__bf16)xs[p].z, (__bf16)xs[p].w };
        *reinterpret_cast<bf16x4*>(&As[0][kslot >> 1][p * 32 + nrow8][(kslot & 1) * 4]) = b;
    }
    __syncthreads();

    // ---- MFMA loop: 4 chunks of 32 k; acc[mi][oi], wave owns 64 n x 32 o'
    f32x4 acc[4][2] = {};

    #pragma unroll 1
    for (int c = 0; c < 4; ++c) {
        const int buf = c & 1;
        if (c < 3) {
            #pragma unroll
            for (int p = 0; p < 8; ++p)
                xs[p] = *reinterpret_cast<const float4*>(
                    &x[(p * 32 + nrow8) * IN_F + k0 + (c + 1) * 32 + kslot * 4]);
        }

        bf16x8 bfrag[2];
        #pragma unroll
        for (int oi = 0; oi < 2; ++oi)
            bfrag[oi] = *reinterpret_cast<const bf16x8*>(&Bs[oi * 16 + fr][c * 32 + fg * 8]);
        #pragma unroll
        for (int mi = 0; mi < 4; ++mi) {
            bf16x8 af = *reinterpret_cast<const bf16x8*>(&As[buf][fg][wid * 64 + mi * 16 + fr][0]);
            acc[mi][0] = __builtin_amdgcn_mfma_f32_16x16x32_bf16(af, bfrag[0], acc[mi][0], 0, 0, 0);
            acc[mi][1] = __builtin_amdgcn_mfma_f32_16x16x32_bf16(af, bfrag[1], acc[mi][1], 0, 0, 0);
        }

        if (c < 3) {
            __syncthreads();             // all waves done with As[buf^1] readers
            #pragma unroll
            for (int p = 0; p < 8; ++p) {
                bf16x4 b = { (__bf16)xs[p].x, (__bf16)xs[p].y, (__bf16)xs[p].z, (__bf16)xs[p].w };
                *reinterpret_cast<bf16x4*>(&As[buf ^ 1][kslot >> 1][p * 32 + nrow8][(kslot & 1) * 4]) = b;
            }
            __syncthreads();
        }
    }

    // ---- epilogue: Pp[ks][o' = fo*32 + oi*16 + fr][n = wid*64+mi*16+fg*4+r] bf16
    __bf16* dst = Pp + (size_t)ks * OPN;
    #pragma unroll
    for (int mi = 0; mi < 4; ++mi) {
        #pragma unroll
        for (int oi = 0; oi < 2; ++oi) {
            const int op = fo * 32 + oi * 16 + fr;
            const int nb = wid * 64 + mi * 16 + fg * 4;
            bf16x4 v = { (__bf16)acc[mi][oi][0], (__bf16)acc[mi][oi][1],
                         (__bf16)acc[mi][oi][2], (__bf16)acc[mi][oi][3] };
            *reinterpret_cast<bf16x4*>(&dst[(size_t)op * NR + nb]) = v;
        }
    }
}

// ---------------------------------------------------------------------------
// K2 (R23 verbatim): TWO-TIER screen. Tier-1 hot loop: projections 0-3 only
// (ONE broadcast ds_read_b128 + 4 |d| + max tree). Tier-1 survivors (~200)
// check projections 4-7 from LDS (cheap). Exact fallback only if ALL 8 pass
// -- identical accept condition to R17's single-tier, which measured ZERO
// fallback events. Output bit-identical to R17.
// ---------------------------------------------------------------------------
__global__ __launch_bounds__(256, 2) void screen_kernel(const __bf16* __restrict__ Pp,
                                                        const float* __restrict__ x,
                                                        const float* __restrict__ Tm,
                                                        float* __restrict__ out) {
    __shared__ float P8s[256][8];
    __shared__ float part[4][64];

    const int f    = blockIdx.x;
    const int jq   = blockIdx.y;
    const int tid  = threadIdx.x;
    const int lane = tid & 63;
    const int wid  = tid >> 6;
    const int j    = jq * 64 + lane;

    // stage merged projections (16 bf16 partials, vectorized u16x8)
    {
        const int p  = tid >> 5;
        const int n0 = (tid & 31) * 8;
        const uint16_t* base = reinterpret_cast<const uint16_t*>(Pp)
                             + (size_t)(f * 8 + p) * NR + n0;
        float a[8] = {};
        #pragma unroll
        for (int ks = 0; ks < KSN; ++ks) {
            u16x8 v = *reinterpret_cast<const u16x8*>(base + (size_t)ks * OPN);
            #pragma unroll
            for (int e = 0; e < 8; ++e)
                a[e] += __builtin_bit_cast(float, (uint32_t)v[e] << 16);
        }
        #pragma unroll
        for (int e = 0; e < 8; ++e)
            P8s[n0 + e][p] = a[e];
    }
    __syncthreads();

    const f32x4 qj0 = *reinterpret_cast<const f32x4*>(&P8s[j][0]);
    const f32x4 qj1 = *reinterpret_cast<const f32x4*>(&P8s[j][4]);

    float acc = 0.f;
    const int i0 = wid * 64;
    #pragma unroll 2
    for (int ii = 0; ii < 64; ++ii) {
        const int i = i0 + ii;
        // tier 1: projections 0-3 (one broadcast b128)
        f32x4 r0 = *reinterpret_cast<const f32x4*>(&P8s[i][0]);
        f32x4 d0 = r0 - qj0;
        const float mx1 = fmaxf(fmaxf(fabsf(d0[0]), fabsf(d0[1])),
                                fmaxf(fabsf(d0[2]), fabsf(d0[3])));
        const bool ok1 = (mx1 < THRESH) && (i != j);

        if (__builtin_expect(__any(ok1), 0)) {
            // tier 2: projections 4-7 (rare; ~200 events total)
            bool ok2 = false;
            if (ok1) {
                f32x4 r1 = *reinterpret_cast<const f32x4*>(&P8s[i][4]);
                f32x4 d1 = r1 - qj1;
                const float mx2 = fmaxf(fmaxf(fabsf(d1[0]), fabsf(d1[1])),
                                        fmaxf(fabsf(d1[2]), fabsf(d1[3])));
                ok2 = mx2 < THRESH;
            }
            if (__builtin_expect(__any(ok2), 0)) {
                if (ok2) {
                    // exact fallback (all 8 projections passed; ~never on this data)
                    f32x4 ad[8] = {};
                    const float* xi = x + (size_t)i * IN_F;
                    const float* xj = x + (size_t)j * IN_F;
                    for (int k = 0; k < IN_F; ++k) {
                        const float dk = xi[k] - xj[k];
                        const float* tr = Tm + (size_t)k * OD + f * KD;
                        #pragma unroll
                        for (int q = 0; q < 8; ++q) {
                            f32x4 tv = *reinterpret_cast<const f32x4*>(tr + q * 4);
                            ad[q] += dk * tv;
                        }
                    }
                    float norm = 0.f;
                    #pragma unroll
                    for (int q = 0; q < 8; ++q)
                        norm += fabsf(ad[q][0]) + fabsf(ad[q][1])
                              + fabsf(ad[q][2]) + fabsf(ad[q][3]);
                    acc += __expf(-norm);
                }
            }
        }
    }

    if (wid == jq) acc += 1.0f;          // diagonal exp(0)=1, exact

    part[wid][lane] = acc;
    __syncthreads();
    if (tid < 64) {
        float s = part[0][tid] + part[1][tid] + part[2][tid] + part[3][tid];
        out[(jq * 64 + tid) * OC + IN_F + f] = s;
    }
}

extern "C" void kernel_launch(void* const* d_in, const int* in_sizes, int n_in,
                              void* d_out, int out_size, void* d_ws, size_t ws_size,
                              hipStream_t stream) {
    const float* x  = (const float*)d_in[0];   // [256, 2048] f32
    const float* Tm = (const float*)d_in[1];   // [2048, 4096] f32
    float* out = (float*)d_out;                // [256, 2176] f32

    __bf16* Pp = (__bf16*)d_ws;                // 8 MB: 16 bf16 o'-major partials

    fused_kernel<<<dim3(512), 256, 0, stream>>>(x, Tm, out, Pp);
    screen_kernel<<<dim3(128, 4), 256, 0, stream>>>(Pp, x, Tm, out);
}

// Round 26
// 27.057 us; speedup vs baseline: 1.1443x; 1.0227x over previous
//
#include <hip/hip_runtime.h>
#include <hip/hip_bf16.h>
#include <stdint.h>

#define IN_F 2048
#define OUT_F 128
#define KD 32
#define NR 256
#define OC 2176          // IN_F + OUT_F
#define OD 4096          // OUT_F * KD (T row stride)
#define THRESH 32.0f
#define KSN 16           // k-slices of 128
#define OPN (1024 * 256) // elems per Pp partial (8 projections per f)

#define BS_BYTES (32 * 136 * 2)                 // 8704
#define AS_BYTES (4 * 4 * 256 * 8 * 2)          // 65536
#define LDS_TOTAL (BS_BYTES + AS_BYTES)         // 74240 (dynamic; 2 blocks/CU)

typedef __bf16 bf16x8 __attribute__((ext_vector_type(8)));
typedef __bf16 bf16x4 __attribute__((ext_vector_type(4)));
typedef float  f32x4  __attribute__((ext_vector_type(4)));
typedef uint16_t u16x8 __attribute__((ext_vector_type(8)));

// ---------------------------------------------------------------------------
// K1 (R26): fused tproj + sgemm + x-copy, single-barrier structure.
// Same block decomposition / staging maps / MFMA mapping as R17 (proven),
// but: (a) BOTH tproj rounds' T-loads issue up front (no serialized 2nd HBM
// round); (b) all 4 x-chunks staged into a 64 KB As before ONE syncthreads;
// the MFMA loop then runs barrier-free out of LDS (reads only).
// ---------------------------------------------------------------------------
__global__ __launch_bounds__(256, 2) void fused_kernel(const float* __restrict__ x,
                                                       const float* __restrict__ Tm,
                                                       float* __restrict__ out,
                                                       __bf16* __restrict__ Pp) {
    extern __shared__ char smem[];
    __bf16* Bs = (__bf16*)smem;                  // [32][136] (pad 8)
    __bf16* As = (__bf16*)(smem + BS_BYTES);     // [4 chunk][4 fg][256 n][8]

    const int tid  = threadIdx.x;
    const int lane = tid & 63;
    const int wid  = tid >> 6;
    const int fr   = lane & 15, fg = lane >> 4;
    const int bid  = blockIdx.x;
    const int ks   = bid & 15;
    const int fo   = bid >> 4;           // f-group of 4
    const int k0   = ks * 128;

#define BS_AT(o, k)        Bs[(o) * 136 + (k)]
#define AS_AT(c, g, n, e)  As[((((c) * 4 + (g)) * 256 + (n)) * 8 + (e))]

    // ---- x -> out copy (block covers 4 KB: row bid>>1, half bid&1)
    {
        const int row = bid >> 1;
        const int off = (bid & 1) * 1024 + tid * 4;
        float4 v = *reinterpret_cast<const float4*>(&x[row * IN_F + off]);
        *reinterpret_cast<float4*>(&out[row * OC + off]) = v;
    }

    // ---- issue x chunk-0 loads + BOTH tproj rounds' T loads up front
    const int kslot = tid & 7;
    const int nrow8 = tid >> 3;          // n = p*32 + nrow8
    const int fl = tid & 3;
    const int kl = tid >> 2;             // 0..63; round 2 = kl + 64, same fl

    float4 xs[8];
    #pragma unroll
    for (int p = 0; p < 8; ++p)
        xs[p] = *reinterpret_cast<const float4*>(&x[(p * 32 + nrow8) * IN_F + k0 + kslot * 4]);

    const float* srcA = Tm + (size_t)(k0 + kl) * OD + (fo * 4 + fl) * KD;
    const float* srcB = srcA + (size_t)64 * OD;

    float va[32], vb[32];
    #pragma unroll
    for (int q = 0; q < 8; ++q) {
        f32x4 w = *reinterpret_cast<const f32x4*>(srcA + q * 4);
        va[q*4] = w[0]; va[q*4+1] = w[1]; va[q*4+2] = w[2]; va[q*4+3] = w[3];
    }
    #pragma unroll
    for (int q = 0; q < 8; ++q) {
        f32x4 w = *reinterpret_cast<const f32x4*>(srcB + q * 4);
        vb[q*4] = w[0]; vb[q*4+1] = w[1]; vb[q*4+2] = w[2]; vb[q*4+3] = w[3];
    }

    // ---- butterfly-FWHT round 1 (masks {0,1,2,4,8,16,3,24}; verbatim math)
    {
        float s1[16], d1[16];
        #pragma unroll
        for (int e = 0; e < 16; ++e) { s1[e] = va[2*e] + va[2*e+1]; d1[e] = va[2*e] - va[2*e+1]; }
        float s2[8], d2[8];
        #pragma unroll
        for (int e = 0; e < 8; ++e)  { s2[e] = s1[2*e] + s1[2*e+1]; d2[e] = s1[2*e] - s1[2*e+1]; }
        float s3[4], d3[4];
        #pragma unroll
        for (int e = 0; e < 4; ++e)  { s3[e] = s2[2*e] + s2[2*e+1]; d3[e] = s2[2*e] - s2[2*e+1]; }
        float s4[2], d4[2];
        #pragma unroll
        for (int e = 0; e < 2; ++e)  { s4[e] = s3[2*e] + s3[2*e+1]; d4[e] = s3[2*e] - s3[2*e+1]; }
        float pr[8];
        pr[0] = s4[0] + s4[1];
        { float s = 0.f;
          #pragma unroll
          for (int e = 0; e < 16; ++e) s += d1[e];
          pr[1] = s; }
        { float s = 0.f;
          #pragma unroll
          for (int e = 0; e < 8; ++e) s += d2[e];
          pr[2] = s; }
        pr[3] = (d3[0] + d3[1]) + (d3[2] + d3[3]);
        pr[4] = d4[0] + d4[1];
        pr[5] = s4[0] - s4[1];
        { float s = 0.f;
          #pragma unroll
          for (int g = 0; g < 8; ++g) s += d1[2*g] - d1[2*g+1];
          pr[6] = s; }
        pr[7] = s3[0] - s3[1] - s3[2] + s3[3];
        #pragma unroll
        for (int p = 0; p < 8; ++p)
            BS_AT(fl * 8 + p, kl) = (__bf16)pr[p];
    }

    // ---- write x chunk 0; issue chunk 1 (overlaps butterfly 2's waits)
    #pragma unroll
    for (int p = 0; p < 8; ++p) {
        bf16x4 b = { (__bf16)xs[p].x, (__bf16)xs[p].y, (__bf16)xs[p].z, (__bf16)xs[p].w };
        *reinterpret_cast<bf16x4*>(&AS_AT(0, kslot >> 1, p * 32 + nrow8, (kslot & 1) * 4)) = b;
    }
    #pragma unroll
    for (int p = 0; p < 8; ++p)
        xs[p] = *reinterpret_cast<const float4*>(&x[(p * 32 + nrow8) * IN_F + k0 + 32 + kslot * 4]);

    // ---- butterfly-FWHT round 2
    {
        float s1[16], d1[16];
        #pragma unroll
        for (int e = 0; e < 16; ++e) { s1[e] = vb[2*e] + vb[2*e+1]; d1[e] = vb[2*e] - vb[2*e+1]; }
        float s2[8], d2[8];
        #pragma unroll
        for (int e = 0; e < 8; ++e)  { s2[e] = s1[2*e] + s1[2*e+1]; d2[e] = s1[2*e] - s1[2*e+1]; }
        float s3[4], d3[4];
        #pragma unroll
        for (int e = 0; e < 4; ++e)  { s3[e] = s2[2*e] + s2[2*e+1]; d3[e] = s2[2*e] - s2[2*e+1]; }
        float s4[2], d4[2];
        #pragma unroll
        for (int e = 0; e < 2; ++e)  { s4[e] = s3[2*e] + s3[2*e+1]; d4[e] = s3[2*e] - s3[2*e+1]; }
        float pr[8];
        pr[0] = s4[0] + s4[1];
        { float s = 0.f;
          #pragma unroll
          for (int e = 0; e < 16; ++e) s += d1[e];
          pr[1] = s; }
        { float s = 0.f;
          #pragma unroll
          for (int e = 0; e < 8; ++e) s += d2[e];
          pr[2] = s; }
        pr[3] = (d3[0] + d3[1]) + (d3[2] + d3[3]);
        pr[4] = d4[0] + d4[1];
        pr[5] = s4[0] - s4[1];
        { float s = 0.f;
          #pragma unroll
          for (int g = 0; g < 8; ++g) s += d1[2*g] - d1[2*g+1];
          pr[6] = s; }
        pr[7] = s3[0] - s3[1] - s3[2] + s3[3];
        #pragma unroll
        for (int p = 0; p < 8; ++p)
            BS_AT(fl * 8 + p, kl + 64) = (__bf16)pr[p];
    }

    // ---- rolling stage of x chunks 1..3 into As (no barriers needed:
    //      each thread writes only its own slots)
    #pragma unroll 1
    for (int c = 1; c < 4; ++c) {
        float4 nxt[8];
        if (c < 3) {
            #pragma unroll
            for (int p = 0; p < 8; ++p)
                nxt[p] = *reinterpret_cast<const float4*>(
                    &x[(p * 32 + nrow8) * IN_F + k0 + (c + 1) * 32 + kslot * 4]);
        }
        #pragma unroll
        for (int p = 0; p < 8; ++p) {
            bf16x4 b = { (__bf16)xs[p].x, (__bf16)xs[p].y, (__bf16)xs[p].z, (__bf16)xs[p].w };
            *reinterpret_cast<bf16x4*>(&AS_AT(c, kslot >> 1, p * 32 + nrow8, (kslot & 1) * 4)) = b;
        }
        if (c < 3) {
            #pragma unroll
            for (int p = 0; p < 8; ++p) xs[p] = nxt[p];
        }
    }

    __syncthreads();                     // the ONLY barrier

    // ---- MFMA loop: 4 chunks of 32 k, barrier-free (LDS reads only)
    f32x4 acc[4][2] = {};

    #pragma unroll
    for (int c = 0; c < 4; ++c) {
        bf16x8 bfrag[2];
        #pragma unroll
        for (int oi = 0; oi < 2; ++oi)
            bfrag[oi] = *reinterpret_cast<const bf16x8*>(&BS_AT(oi * 16 + fr, c * 32 + fg * 8));
        #pragma unroll
        for (int mi = 0; mi < 4; ++mi) {
            bf16x8 af = *reinterpret_cast<const bf16x8*>(&AS_AT(c, fg, wid * 64 + mi * 16 + fr, 0));
            acc[mi][0] = __builtin_amdgcn_mfma_f32_16x16x32_bf16(af, bfrag[0], acc[mi][0], 0, 0, 0);
            acc[mi][1] = __builtin_amdgcn_mfma_f32_16x16x32_bf16(af, bfrag[1], acc[mi][1], 0, 0, 0);
        }
    }

    // ---- epilogue: Pp[ks][o' = fo*32 + oi*16 + fr][n = wid*64+mi*16+fg*4+r] bf16
    __bf16* dst = Pp + (size_t)ks * OPN;
    #pragma unroll
    for (int mi = 0; mi < 4; ++mi) {
        #pragma unroll
        for (int oi = 0; oi < 2; ++oi) {
            const int op = fo * 32 + oi * 16 + fr;
            const int nb = wid * 64 + mi * 16 + fg * 4;
            bf16x4 v = { (__bf16)acc[mi][oi][0], (__bf16)acc[mi][oi][1],
                         (__bf16)acc[mi][oi][2], (__bf16)acc[mi][oi][3] };
            *reinterpret_cast<bf16x4*>(&dst[(size_t)op * NR + nb]) = v;
        }
    }
#undef BS_AT
#undef AS_AT
}

// ---------------------------------------------------------------------------
// K2 (verbatim R23): TWO-TIER screen. Tier-1 hot loop: projections 0-3 only
// (ONE broadcast ds_read_b128 + 4 |d| + max tree). Tier-1 survivors (~200)
// check projections 4-7 from LDS; exact fallback only if ALL 8 pass
// (identical accept condition to R17, which measured zero fallback events).
// ---------------------------------------------------------------------------
__global__ __launch_bounds__(256, 2) void screen_kernel(const __bf16* __restrict__ Pp,
                                                        const float* __restrict__ x,
                                                        const float* __restrict__ Tm,
                                                        float* __restrict__ out) {
    __shared__ float P8s[256][8];
    __shared__ float part[4][64];

    const int f    = blockIdx.x;
    const int jq   = blockIdx.y;
    const int tid  = threadIdx.x;
    const int lane = tid & 63;
    const int wid  = tid >> 6;
    const int j    = jq * 64 + lane;

    // stage merged projections (16 bf16 partials, vectorized u16x8)
    {
        const int p  = tid >> 5;
        const int n0 = (tid & 31) * 8;
        const uint16_t* base = reinterpret_cast<const uint16_t*>(Pp)
                             + (size_t)(f * 8 + p) * NR + n0;
        float a[8] = {};
        #pragma unroll
        for (int ks = 0; ks < KSN; ++ks) {
            u16x8 v = *reinterpret_cast<const u16x8*>(base + (size_t)ks * OPN);
            #pragma unroll
            for (int e = 0; e < 8; ++e)
                a[e] += __builtin_bit_cast(float, (uint32_t)v[e] << 16);
        }
        #pragma unroll
        for (int e = 0; e < 8; ++e)
            P8s[n0 + e][p] = a[e];
    }
    __syncthreads();

    const f32x4 qj0 = *reinterpret_cast<const f32x4*>(&P8s[j][0]);
    const f32x4 qj1 = *reinterpret_cast<const f32x4*>(&P8s[j][4]);

    float acc = 0.f;
    const int i0 = wid * 64;
    #pragma unroll 2
    for (int ii = 0; ii < 64; ++ii) {
        const int i = i0 + ii;
        // tier 1: projections 0-3 (one broadcast b128)
        f32x4 r0 = *reinterpret_cast<const f32x4*>(&P8s[i][0]);
        f32x4 d0 = r0 - qj0;
        const float mx1 = fmaxf(fmaxf(fabsf(d0[0]), fabsf(d0[1])),
                                fmaxf(fabsf(d0[2]), fabsf(d0[3])));
        const bool ok1 = (mx1 < THRESH) && (i != j);

        if (__builtin_expect(__any(ok1), 0)) {
            // tier 2: projections 4-7 (rare; ~200 events total)
            bool ok2 = false;
            if (ok1) {
                f32x4 r1 = *reinterpret_cast<const f32x4*>(&P8s[i][4]);
                f32x4 d1 = r1 - qj1;
                const float mx2 = fmaxf(fmaxf(fabsf(d1[0]), fabsf(d1[1])),
                                        fmaxf(fabsf(d1[2]), fabsf(d1[3])));
                ok2 = mx2 < THRESH;
            }
            if (__builtin_expect(__any(ok2), 0)) {
                if (ok2) {
                    // exact fallback (all 8 projections passed; ~never on this data)
                    f32x4 ad[8] = {};
                    const float* xi = x + (size_t)i * IN_F;
                    const float* xj = x + (size_t)j * IN_F;
                    for (int k = 0; k < IN_F; ++k) {
                        const float dk = xi[k] - xj[k];
                        const float* tr = Tm + (size_t)k * OD + f * KD;
                        #pragma unroll
                        for (int q = 0; q < 8; ++q) {
                            f32x4 tv = *reinterpret_cast<const f32x4*>(tr + q * 4);
                            ad[q] += dk * tv;
                        }
                    }
                    float norm = 0.f;
                    #pragma unroll
                    for (int q = 0; q < 8; ++q)
                        norm += fabsf(ad[q][0]) + fabsf(ad[q][1])
                              + fabsf(ad[q][2]) + fabsf(ad[q][3]);
                    acc += __expf(-norm);
                }
            }
        }
    }

    if (wid == jq) acc += 1.0f;          // diagonal exp(0)=1, exact

    part[wid][lane] = acc;
    __syncthreads();
    if (tid < 64) {
        float s = part[0][tid] + part[1][tid] + part[2][tid] + part[3][tid];
        out[(jq * 64 + tid) * OC + IN_F + f] = s;
    }
}

extern "C" void kernel_launch(void* const* d_in, const int* in_sizes, int n_in,
                              void* d_out, int out_size, void* d_ws, size_t ws_size,
                              hipStream_t stream) {
    const float* x  = (const float*)d_in[0];   // [256, 2048] f32
    const float* Tm = (const float*)d_in[1];   // [2048, 4096] f32
    float* out = (float*)d_out;                // [256, 2176] f32

    __bf16* Pp = (__bf16*)d_ws;                // 8 MB: 16 bf16 o'-major partials

    fused_kernel<<<dim3(512), 256, LDS_TOTAL, stream>>>(x, Tm, out, Pp);
    screen_kernel<<<dim3(128, 4), 256, 0, stream>>>(Pp, x, Tm, out);
}